// Round 3
// baseline (1270.695 us; speedup 1.0000x reference)
//
#include <hip/hip_runtime.h>
#include <stdint.h>

typedef __bf16 bf16;
typedef __bf16 bf16x8 __attribute__((ext_vector_type(8)));
typedef __bf16 bf16x4 __attribute__((ext_vector_type(4)));
typedef float  f32x4  __attribute__((ext_vector_type(4)));
typedef float  fvec4  __attribute__((ext_vector_type(4)));

// ---------------- workspace layout (bytes) ----------------
static const size_t OFF_A       = 0;         // 131072 f32 (per-token attn logit)
static const size_t OFF_SEGMAX  = 524288;    // 88 u32 (ordered-key max), pad 128
static const size_t OFF_DENOM   = 524800;    // 88 f32
static const size_t OFF_CNT     = 525312;    // 88 i32
static const size_t OFF_CFEAT   = 525824;    // 88*512 f32
static const size_t OFF_CFEAT2  = 706048;    // 88*512 f32
static const size_t ZERO_BYTES  = 886272;    // everything above zeroed each call
static const size_t OFF_FLAG    = 886272;    // 64 B (dtype flag)
static const size_t OFF_CANON   = 886336;    // 4096 bf16 canonical small params
static const size_t OFF_TEMB    = 894528;    // [11][512] f32 (emb tail + b_fuse)
static const size_t OFF_X       = 917056;    // 131072*512 bf16 = 128 MiB
static const size_t OFF_WFT     = OFF_X + (size_t)134217728;   // [512][512] bf16
static const size_t OFF_WA1T    = OFF_WFT + 524288;            // [256][512] bf16
static const size_t OFF_WB1T    = OFF_WA1T + 262144;
static const size_t OFF_WINTRAT = OFF_WB1T + 262144;           // [512][512] bf16
static const size_t OFF_WA2T    = OFF_WINTRAT + 524288;        // [256][512] bf16
static const size_t OFF_WB2T    = OFF_WA2T + 262144;
static const size_t OFF_WINTERT = OFF_WB2T + 262144;           // [256][512] bf16

// canonical small-param offsets (bf16 elements within CANON)
#define CAN_BA1    0
#define CAN_BB1    256
#define CAN_WC1    512
#define CAN_BINTRA 768
#define CAN_BA2    1280
#define CAN_BB2    1536
#define CAN_WC2    1792
#define CAN_BINTER 2048
#define CAN_WCLS   2304
#define CAN_BCLS   2816

__device__ __forceinline__ int clip11(int c) { return c < 0 ? 0 : (c > 10 ? 10 : c); }

// NaN-PROPAGATING relu: keeps NaN visible (fmaxf would squash it)
__device__ __forceinline__ float relu_f(float v) { return v < 0.0f ? 0.0f : v; }

// read element i of a float-tensor input whose real dtype is f32 (fl=1) or bf16 (fl=0)
__device__ __forceinline__ float cvt(const void* p, int i, int fl) {
  return fl ? ((const float*)p)[i] : (float)((const bf16*)p)[i];
}

// monotone float->uint key for atomicMax (init 0 == "below all reals")
__device__ __forceinline__ unsigned fkey(float f) {
  unsigned u = __float_as_uint(f);
  return (u & 0x80000000u) ? ~u : (u | 0x80000000u);
}
__device__ __forceinline__ float key_to_f(unsigned k) {
  unsigned u = (k & 0x80000000u) ? (k & 0x7FFFFFFFu) : ~k;
  return __uint_as_float(u);
}

// ============ dtype detector: are float inputs f32 (flag=1) or bf16 (flag=0)? ============
// If h is f32, the even-index uint16 halves are mantissa bits -> implausible bf16 exponents.
__global__ void k_detect(const unsigned short* __restrict__ hh, int* __restrict__ flag) {
  const int lane = threadIdx.x;  // 64 lanes
  const unsigned short u = hh[lane * 2];
  const int e = (u >> 7) & 0xFF;
  int pl = (e > 96 && e < 140) ? 1 : 0;
#pragma unroll
  for (int off = 1; off < 64; off <<= 1) pl += __shfl_xor(pl, off, 64);
  if (lane == 0) *flag = (pl < 32) ? 1 : 0;
}

// stage ROWS x 64 bf16 tile, row-major [row][64], from bf16 source
template <int ROWS>
__device__ __forceinline__ void stage_bf16(const bf16* __restrict__ g, bf16* lds,
                                           int ldg, int tid) {
  const int row = tid >> 3;
  const int ko  = (tid & 7) * 8;
#pragma unroll
  for (int j = 0; j < ROWS; j += 32) {
    bf16x8 v = *(const bf16x8*)(g + (size_t)(j + row) * ldg + ko);
    *(bf16x8*)(lds + (j + row) * 64 + ko) = v;
  }
}

// stage ROWS x 64 tile from f32 source, converting to bf16
template <int ROWS>
__device__ __forceinline__ void stage_f32(const float* __restrict__ g, bf16* lds,
                                          int ldg, int tid) {
  const int row = tid >> 4;
  const int co  = (tid & 15) * 4;
#pragma unroll
  for (int j = 0; j < ROWS; j += 16) {
    fvec4 v = *(const fvec4*)(g + (size_t)(j + row) * ldg + co);
    bf16x4 b;
    b[0] = (bf16)v[0]; b[1] = (bf16)v[1]; b[2] = (bf16)v[2]; b[3] = (bf16)v[3];
    *(bf16x4*)(lds + (j + row) * 64 + co) = b;
  }
}

// ============ kernel 1: x = relu(h @ Wfuse + T[cid]) ============
// tile 128(m) x 256(n), 4 waves as 2x2, wave tile 64x128 (4x8 mfma tiles)
__global__ __launch_bounds__(256) void k_fuse(
    const void* __restrict__ h, const int* __restrict__ cids,
    const bf16* __restrict__ WfT, const float* __restrict__ Temb,
    const int* __restrict__ flag, bf16* __restrict__ x) {
  __shared__ __align__(16) bf16 As[128 * 64];
  __shared__ __align__(16) bf16 Bs[256 * 64];
  const int tid = threadIdx.x, lane = tid & 63, wid = tid >> 6;
  const int quad = lane >> 4, l15 = lane & 15;
  const int wm = wid >> 1, wn = wid & 1;
  const int m0 = blockIdx.x * 128, n0 = blockIdx.y * 256;
  const int fl = *flag;

  f32x4 acc[4][8] = {};
  for (int k0 = 0; k0 < 512; k0 += 64) {
    if (fl) stage_f32<128>((const float*)h + (size_t)m0 * 512 + k0, As, 512, tid);
    else    stage_bf16<128>((const bf16*)h + (size_t)m0 * 512 + k0, As, 512, tid);
    stage_bf16<256>(WfT + (size_t)n0 * 512 + k0, Bs, 512, tid);
    __syncthreads();
#pragma unroll
    for (int kk = 0; kk < 64; kk += 32) {
      bf16x8 af[4], bfr[8];
#pragma unroll
      for (int t = 0; t < 4; ++t)
        af[t] = *(const bf16x8*)&As[(wm * 64 + t * 16 + l15) * 64 + kk + quad * 8];
#pragma unroll
      for (int t = 0; t < 8; ++t)
        bfr[t] = *(const bf16x8*)&Bs[(wn * 128 + t * 16 + l15) * 64 + kk + quad * 8];
#pragma unroll
      for (int tm = 0; tm < 4; ++tm)
#pragma unroll
        for (int tn = 0; tn < 8; ++tn)
          acc[tm][tn] = __builtin_amdgcn_mfma_f32_16x16x32_bf16(af[tm], bfr[tn], acc[tm][tn], 0, 0, 0);
    }
    __syncthreads();
  }
#pragma unroll
  for (int tm = 0; tm < 4; ++tm) {
#pragma unroll
    for (int r = 0; r < 4; ++r) {
      const int m = m0 + wm * 64 + tm * 16 + quad * 4 + r;
      const int c = clip11(cids[m]);
      const float* Trow = Temb + c * 512;
#pragma unroll
      for (int tn = 0; tn < 8; ++tn) {
        const int nn = n0 + wn * 128 + tn * 16 + l15;
        x[(size_t)m * 512 + nn] = (bf16)relu_f(acc[tm][tn][r] + Trow[nn]);
      }
    }
  }
}

// ============ kernel 2: A[m] += sum_n tanh(x@Wa1+ba1)*sigmoid(x@Wb1+bb1)*wc1 ============
__global__ __launch_bounds__(256) void k_gate1(
    const bf16* __restrict__ x, const bf16* __restrict__ Wa1T, const bf16* __restrict__ Wb1T,
    const bf16* __restrict__ canon, float* __restrict__ Apart) {
  __shared__ __align__(16) bf16 As[128 * 64];
  __shared__ __align__(16) bf16 Ba[128 * 64];
  __shared__ __align__(16) bf16 Bb[128 * 64];
  const int tid = threadIdx.x, lane = tid & 63, wid = tid >> 6;
  const int quad = lane >> 4, l15 = lane & 15;
  const int wm = wid >> 1, wn = wid & 1;
  const int m0 = blockIdx.x * 128, n0 = blockIdx.y * 128;

  f32x4 aa[4][4] = {}, ag[4][4] = {};
  for (int k0 = 0; k0 < 512; k0 += 64) {
    stage_bf16<128>(x + (size_t)m0 * 512 + k0, As, 512, tid);
    stage_bf16<128>(Wa1T + (size_t)n0 * 512 + k0, Ba, 512, tid);
    stage_bf16<128>(Wb1T + (size_t)n0 * 512 + k0, Bb, 512, tid);
    __syncthreads();
#pragma unroll
    for (int kk = 0; kk < 64; kk += 32) {
      bf16x8 af[4], bA[4], bB[4];
#pragma unroll
      for (int t = 0; t < 4; ++t)
        af[t] = *(const bf16x8*)&As[(wm * 64 + t * 16 + l15) * 64 + kk + quad * 8];
#pragma unroll
      for (int t = 0; t < 4; ++t) {
        bA[t] = *(const bf16x8*)&Ba[(wn * 64 + t * 16 + l15) * 64 + kk + quad * 8];
        bB[t] = *(const bf16x8*)&Bb[(wn * 64 + t * 16 + l15) * 64 + kk + quad * 8];
      }
#pragma unroll
      for (int tm = 0; tm < 4; ++tm)
#pragma unroll
        for (int tn = 0; tn < 4; ++tn) {
          aa[tm][tn] = __builtin_amdgcn_mfma_f32_16x16x32_bf16(af[tm], bA[tn], aa[tm][tn], 0, 0, 0);
          ag[tm][tn] = __builtin_amdgcn_mfma_f32_16x16x32_bf16(af[tm], bB[tn], ag[tm][tn], 0, 0, 0);
        }
    }
    __syncthreads();
  }
  float bav[4], bbv[4], wcv[4];
#pragma unroll
  for (int tn = 0; tn < 4; ++tn) {
    const int nn = n0 + wn * 64 + tn * 16 + l15;
    bav[tn] = (float)canon[CAN_BA1 + nn];
    bbv[tn] = (float)canon[CAN_BB1 + nn];
    wcv[tn] = (float)canon[CAN_WC1 + nn];
  }
#pragma unroll
  for (int tm = 0; tm < 4; ++tm) {
#pragma unroll
    for (int r = 0; r < 4; ++r) {
      float rs = 0.f;
#pragma unroll
      for (int tn = 0; tn < 4; ++tn) {
        const float av = aa[tm][tn][r] + bav[tn];
        const float gv = ag[tm][tn][r] + bbv[tn];
        rs += tanhf(av) * (1.f / (1.f + __expf(-gv))) * wcv[tn];
      }
      rs += __shfl_xor(rs, 1, 64);
      rs += __shfl_xor(rs, 2, 64);
      rs += __shfl_xor(rs, 4, 64);
      rs += __shfl_xor(rs, 8, 64);
      if (l15 == 0) atomicAdd(&Apart[m0 + wm * 64 + tm * 16 + quad * 4 + r], rs);
    }
  }
}

// ============ kernel 3a: per-segment max ============
__global__ __launch_bounds__(256) void k_segmax(
    const float* __restrict__ Apart, const int* __restrict__ cids, unsigned* __restrict__ gmax) {
  __shared__ unsigned sm[88];
  const int tid = threadIdx.x;
  if (tid < 88) sm[tid] = 0u;
  __syncthreads();
  const int base = blockIdx.x * 1024;
  const int b = blockIdx.x >> 4;  // 16 blocks per batch
#pragma unroll
  for (int it = 0; it < 4; ++it) {
    const int t = base + it * 256 + tid;
    atomicMax(&sm[b * 11 + clip11(cids[t])], fkey(Apart[t]));
  }
  __syncthreads();
  if (tid < 88) atomicMax(&gmax[tid], sm[tid]);
}

// ============ kernel 3b: per-segment sum of exp + counts ============
__global__ __launch_bounds__(256) void k_segsum(
    const float* __restrict__ Apart, const int* __restrict__ cids,
    const unsigned* __restrict__ gmax, float* __restrict__ denom, int* __restrict__ counts) {
  __shared__ float sd[88];
  __shared__ int sc[88];
  const int tid = threadIdx.x;
  if (tid < 88) { sd[tid] = 0.f; sc[tid] = 0; }
  __syncthreads();
  const int base = blockIdx.x * 1024;
  const int b = blockIdx.x >> 4;
#pragma unroll
  for (int it = 0; it < 4; ++it) {
    const int t = base + it * 256 + tid;
    const int seg = b * 11 + clip11(cids[t]);
    atomicAdd(&sd[seg], __expf(Apart[t] - key_to_f(gmax[seg])));
    atomicAdd(&sc[seg], 1);
  }
  __syncthreads();
  if (tid < 88) {
    atomicAdd(&denom[tid], sd[tid]);
    atomicAdd(&counts[tid], sc[tid]);
  }
}

// ============ kernel 3c: cfeat[seg] += w * x[token]  (LDS accumulation) ============
__global__ __launch_bounds__(256) void k_cfeat(
    const float* __restrict__ Apart, const int* __restrict__ cids,
    const unsigned* __restrict__ gmax, const float* __restrict__ denom,
    const bf16* __restrict__ x, float* __restrict__ cfeat) {
  __shared__ float accf[11 * 256];
  __shared__ float wbuf[1024];
  __shared__ unsigned char cbuf[1024];
  const int tid = threadIdx.x;
  const int base = blockIdx.x * 1024;
  const int b = blockIdx.x >> 4;
  const int nf0 = blockIdx.y * 256;
  for (int i = tid; i < 11 * 256; i += 256) accf[i] = 0.f;
#pragma unroll
  for (int it = 0; it < 4; ++it) {
    const int t = base + it * 256 + tid;
    const int c = clip11(cids[t]);
    const int seg = b * 11 + c;
    wbuf[it * 256 + tid] = __expf(Apart[t] - key_to_f(gmax[seg])) / denom[seg];
    cbuf[it * 256 + tid] = (unsigned char)c;
  }
  __syncthreads();
  const bf16* xp = x + (size_t)base * 512 + nf0 + tid;
#pragma unroll 4
  for (int i = 0; i < 1024; ++i) {
    const float w = wbuf[i];
    const int c = cbuf[i];
    accf[c * 256 + tid] += w * (float)xp[(size_t)i * 512];
  }
  __syncthreads();
  float* cf = cfeat + (size_t)b * 11 * 512 + nf0;
  for (int i = tid; i < 11 * 256; i += 256)
    atomicAdd(&cf[(i >> 8) * 512 + (i & 255)], accf[i]);
}

// ============ kernel 4a: cfeat2 = relu(cfeat @ Wintra + b_intra), 88 rows ============
__global__ __launch_bounds__(256) void k_intra(
    const float* __restrict__ cfeat, const bf16* __restrict__ WintraT,
    const bf16* __restrict__ canon, float* __restrict__ cfeat2) {
  __shared__ float row[512];
  const int r = blockIdx.x, tid = threadIdx.x;
  row[tid] = cfeat[(size_t)r * 512 + tid];
  row[tid + 256] = cfeat[(size_t)r * 512 + 256 + tid];
  __syncthreads();
#pragma unroll
  for (int hh = 0; hh < 2; ++hh) {
    const int n = hh * 256 + tid;
    float acc = (float)canon[CAN_BINTRA + n];
    const bf16* wp = WintraT + (size_t)n * 512;
    for (int k = 0; k < 512; k += 8) {
      bf16x8 wv = *(const bf16x8*)(wp + k);
#pragma unroll
      for (int j = 0; j < 8; ++j) acc += row[k + j] * (float)wv[j];
    }
    cfeat2[(size_t)r * 512 + n] = relu_f(acc);
  }
}

__device__ __forceinline__ float block_sum(float v, float* red, int tid) {
#pragma unroll
  for (int off = 32; off > 0; off >>= 1) v += __shfl_xor(v, off, 64);
  __syncthreads();
  if ((tid & 63) == 0) red[tid >> 6] = v;
  __syncthreads();
  return red[0] + red[1] + red[2] + red[3];
}

// ============ kernel 4b: inter-cluster attention + classifier, 1 block per batch ============
__global__ __launch_bounds__(256) void k_tail(
    const float* __restrict__ cfeat2, const int* __restrict__ counts,
    const bf16* __restrict__ Wa2T, const bf16* __restrict__ Wb2T,
    const bf16* __restrict__ WinterT, const bf16* __restrict__ canon,
    const int* __restrict__ flag, void* __restrict__ out) {
  const int b = blockIdx.x, tid = threadIdx.x;
  __shared__ float row[512];
  __shared__ float A2[11], Wsm[11];
  __shared__ float red[4];
  __shared__ float slide[512];
  __shared__ float hid[256];
  const float* cf = cfeat2 + (size_t)b * 11 * 512;

  for (int c = 0; c < 11; ++c) {
    row[tid] = cf[c * 512 + tid];
    row[tid + 256] = cf[c * 512 + 256 + tid];
    __syncthreads();
    float da = (float)canon[CAN_BA2 + tid], dg = (float)canon[CAN_BB2 + tid];
    const bf16* wa = Wa2T + (size_t)tid * 512;
    const bf16* wb = Wb2T + (size_t)tid * 512;
    for (int k = 0; k < 512; k += 8) {
      bf16x8 av = *(const bf16x8*)(wa + k);
      bf16x8 gv = *(const bf16x8*)(wb + k);
#pragma unroll
      for (int j = 0; j < 8; ++j) {
        const float rv = row[k + j];
        da += rv * (float)av[j];
        dg += rv * (float)gv[j];
      }
    }
    const float contrib = tanhf(da) * (1.f / (1.f + __expf(-dg))) * (float)canon[CAN_WC2 + tid];
    const float tot = block_sum(contrib, red, tid);
    if (tid == 0) A2[c] = tot;
    __syncthreads();
  }
  if (tid == 0) {  // masked softmax over 11 clusters (bc2 cancels)
    float mx = -1e30f;
    for (int c = 0; c < 11; ++c)
      if (counts[b * 11 + c] > 0 && A2[c] > mx) mx = A2[c];
    float s = 0.f;
    for (int c = 0; c < 11; ++c) {
      const float e = (counts[b * 11 + c] > 0) ? __expf(A2[c] - mx) : 0.f;
      Wsm[c] = e; s += e;
    }
    for (int c = 0; c < 11; ++c) Wsm[c] /= s;
  }
  __syncthreads();
  float s0 = 0.f, s1 = 0.f;
  for (int c = 0; c < 11; ++c) {
    const float w = Wsm[c];
    s0 += w * cf[c * 512 + tid];
    s1 += w * cf[c * 512 + 256 + tid];
  }
  slide[tid] = s0; slide[tid + 256] = s1;
  __syncthreads();
  {
    float acc = (float)canon[CAN_BINTER + tid];
    const bf16* wp = WinterT + (size_t)tid * 512;
    for (int k = 0; k < 512; k += 8) {
      bf16x8 wv = *(const bf16x8*)(wp + k);
#pragma unroll
      for (int j = 0; j < 8; ++j) acc += slide[k + j] * (float)wv[j];
    }
    hid[tid] = relu_f(acc);
  }
  __syncthreads();
  const float p0 = hid[tid] * (float)canon[CAN_WCLS + tid * 2 + 0];
  const float p1 = hid[tid] * (float)canon[CAN_WCLS + tid * 2 + 1];
  const float t0 = block_sum(p0, red, tid);
  const float t1 = block_sum(p1, red, tid);
  if (tid == 0) {
    const float o0 = t0 + (float)canon[CAN_BCLS + 0];
    const float o1 = t1 + (float)canon[CAN_BCLS + 1];
    if (*flag) {
      ((float*)out)[b * 2 + 0] = o0;
      ((float*)out)[b * 2 + 1] = o1;
    } else {
      ((bf16*)out)[b * 2 + 0] = (bf16)o0;
      ((bf16*)out)[b * 2 + 1] = (bf16)o1;
    }
  }
}

// ============ prep: dtype-adaptive weight transposes + canonical params + emb-tail ============
__global__ __launch_bounds__(256) void k_prep(
    const void* __restrict__ Wf, const void* __restrict__ bfuse, const void* __restrict__ emb,
    const void* __restrict__ Wa1, const void* __restrict__ Wb1, const void* __restrict__ Wintra,
    const void* __restrict__ Wa2, const void* __restrict__ Wb2, const void* __restrict__ Winter,
    const void* __restrict__ ba1, const void* __restrict__ bb1, const void* __restrict__ wc1,
    const void* __restrict__ bintra, const void* __restrict__ ba2, const void* __restrict__ bb2,
    const void* __restrict__ wc2, const void* __restrict__ binter, const void* __restrict__ Wcls,
    const void* __restrict__ bcls, const int* __restrict__ flag,
    bf16* __restrict__ WfT, bf16* __restrict__ Wa1T, bf16* __restrict__ Wb1T,
    bf16* __restrict__ WintraT, bf16* __restrict__ Wa2T, bf16* __restrict__ Wb2T,
    bf16* __restrict__ WinterT, float* __restrict__ Temb, bf16* __restrict__ canon) {
  const int fl = *flag;
  int id = blockIdx.x * 256 + threadIdx.x;
  if (id < 262144) { WfT[id] = (bf16)cvt(Wf, (id & 511) * 512 + (id >> 9), fl); return; }
  id -= 262144;
  if (id < 131072) { Wa1T[id] = (bf16)cvt(Wa1, (id & 511) * 256 + (id >> 9), fl); return; }
  id -= 131072;
  if (id < 131072) { Wb1T[id] = (bf16)cvt(Wb1, (id & 511) * 256 + (id >> 9), fl); return; }
  id -= 131072;
  if (id < 262144) { WintraT[id] = (bf16)cvt(Wintra, (id & 511) * 512 + (id >> 9), fl); return; }
  id -= 262144;
  if (id < 131072) { Wa2T[id] = (bf16)cvt(Wa2, (id & 511) * 256 + (id >> 9), fl); return; }
  id -= 131072;
  if (id < 131072) { Wb2T[id] = (bf16)cvt(Wb2, (id & 511) * 256 + (id >> 9), fl); return; }
  id -= 131072;
  if (id < 131072) { WinterT[id] = (bf16)cvt(Winter, (id & 511) * 256 + (id >> 9), fl); return; }
  id -= 131072;
  if (id < 5632) {
    const int c = id >> 9, n = id & 511;
    float s = cvt(bfuse, n, fl);
#pragma unroll
    for (int j = 0; j < 8; ++j) s += cvt(emb, c * 8 + j, fl) * cvt(Wf, (512 + j) * 512 + n, fl);
    Temb[id] = s;
    return;
  }
  id -= 5632;
  if (id < 4096) {
    bf16 v = (bf16)0.0f;
    if (id < 256)        v = (bf16)cvt(ba1, id, fl);
    else if (id < 512)   v = (bf16)cvt(bb1, id - 256, fl);
    else if (id < 768)   v = (bf16)cvt(wc1, id - 512, fl);
    else if (id < 1280)  v = (bf16)cvt(bintra, id - 768, fl);
    else if (id < 1536)  v = (bf16)cvt(ba2, id - 1280, fl);
    else if (id < 1792)  v = (bf16)cvt(bb2, id - 1536, fl);
    else if (id < 2048)  v = (bf16)cvt(wc2, id - 1792, fl);
    else if (id < 2304)  v = (bf16)cvt(binter, id - 2048, fl);
    else if (id < 2816)  v = (bf16)cvt(Wcls, id - 2304, fl);
    else if (id < 2818)  v = (bf16)cvt(bcls, id - 2816, fl);
    canon[id] = v;
  }
}

extern "C" void kernel_launch(void* const* d_in, const int* in_sizes, int n_in,
                              void* d_out, int out_size, void* d_ws, size_t ws_size,
                              hipStream_t stream) {
  (void)in_sizes; (void)n_in; (void)out_size; (void)ws_size;
  const void* h      = d_in[0];
  const int*  cids   = (const int*)d_in[1];
  const void* emb    = d_in[2];
  const void* Wf     = d_in[3];
  const void* bfuse  = d_in[4];
  const void* Wa1    = d_in[5];
  const void* ba1    = d_in[6];
  const void* Wb1    = d_in[7];
  const void* bb1    = d_in[8];
  const void* wc1    = d_in[9];
  // d_in[10] = bc1: cancels in segment softmax
  const void* Wintra = d_in[11];
  const void* bintra = d_in[12];
  const void* Wa2    = d_in[13];
  const void* ba2    = d_in[14];
  const void* Wb2    = d_in[15];
  const void* bb2    = d_in[16];
  const void* wc2    = d_in[17];
  // d_in[18] = bc2: cancels in inter softmax
  const void* Winter = d_in[19];
  const void* binter = d_in[20];
  const void* Wcls   = d_in[21];
  const void* bcls   = d_in[22];

  char* ws = (char*)d_ws;
  float*    Apart   = (float*)(ws + OFF_A);
  unsigned* gmax    = (unsigned*)(ws + OFF_SEGMAX);
  float*    denom   = (float*)(ws + OFF_DENOM);
  int*      counts  = (int*)(ws + OFF_CNT);
  float*    cfeat   = (float*)(ws + OFF_CFEAT);
  float*    cfeat2  = (float*)(ws + OFF_CFEAT2);
  int*      flag    = (int*)(ws + OFF_FLAG);
  bf16*     canon   = (bf16*)(ws + OFF_CANON);
  float*    Temb    = (float*)(ws + OFF_TEMB);
  bf16*     x       = (bf16*)(ws + OFF_X);
  bf16*     WfT     = (bf16*)(ws + OFF_WFT);
  bf16*     Wa1T    = (bf16*)(ws + OFF_WA1T);
  bf16*     Wb1T    = (bf16*)(ws + OFF_WB1T);
  bf16*     WintraT = (bf16*)(ws + OFF_WINTRAT);
  bf16*     Wa2T    = (bf16*)(ws + OFF_WA2T);
  bf16*     Wb2T    = (bf16*)(ws + OFF_WB2T);
  bf16*     WinterT = (bf16*)(ws + OFF_WINTERT);

  hipMemsetAsync(d_ws, 0, ZERO_BYTES, stream);
  k_detect<<<1, 64, 0, stream>>>((const unsigned short*)h, flag);
  k_prep<<<4646, 256, 0, stream>>>(Wf, bfuse, emb, Wa1, Wb1, Wintra, Wa2, Wb2, Winter,
                                   ba1, bb1, wc1, bintra, ba2, bb2, wc2, binter, Wcls, bcls,
                                   flag, WfT, Wa1T, Wb1T, WintraT, Wa2T, Wb2T, WinterT,
                                   Temb, canon);
  k_fuse<<<dim3(1024, 2), 256, 0, stream>>>(h, cids, WfT, Temb, flag, x);
  k_gate1<<<dim3(1024, 2), 256, 0, stream>>>(x, Wa1T, Wb1T, canon, Apart);
  k_segmax<<<128, 256, 0, stream>>>(Apart, cids, gmax);
  k_segsum<<<128, 256, 0, stream>>>(Apart, cids, gmax, denom, counts);
  k_cfeat<<<dim3(128, 2), 256, 0, stream>>>(Apart, cids, gmax, denom, x, cfeat);
  k_intra<<<88, 256, 0, stream>>>(cfeat, WintraT, canon, cfeat2);
  k_tail<<<8, 256, 0, stream>>>(cfeat2, counts, Wa2T, Wb2T, WinterT, canon, flag, d_out);
}

// Round 4
// 1179.389 us; speedup vs baseline: 1.0774x; 1.0774x over previous
//
#include <hip/hip_runtime.h>
#include <stdint.h>

typedef __bf16 bf16;
typedef __bf16 bf16x8 __attribute__((ext_vector_type(8)));
typedef __bf16 bf16x4 __attribute__((ext_vector_type(4)));
typedef float  f32x4  __attribute__((ext_vector_type(4)));
typedef float  fvec4  __attribute__((ext_vector_type(4)));

// ---------------- workspace layout (bytes) ----------------
static const size_t OFF_A       = 0;         // 131072 f32 (per-token attn logit)
static const size_t OFF_SEGMAX  = 524288;    // 88 u32 (ordered-key max), pad 128
static const size_t OFF_DENOM   = 524800;    // 88 f32
static const size_t OFF_CNT     = 525312;    // 88 i32
static const size_t OFF_CFEAT   = 525824;    // 88*512 f32
static const size_t OFF_CFEAT2  = 706048;    // 88*512 f32
static const size_t ZERO_BYTES  = 886272;    // everything above zeroed each call
static const size_t OFF_FLAG    = 886272;    // 64 B (dtype flag)
static const size_t OFF_CANON   = 886336;    // 4096 bf16 canonical small params
static const size_t OFF_TEMB    = 894528;    // [11][512] f32 (emb tail + b_fuse)
static const size_t OFF_X       = 917056;    // 131072*512 bf16 = 128 MiB
static const size_t OFF_WFT     = OFF_X + (size_t)134217728;   // [512][512] bf16
static const size_t OFF_WA1T    = OFF_WFT + 524288;            // [256][512] bf16
static const size_t OFF_WB1T    = OFF_WA1T + 262144;
static const size_t OFF_WINTRAT = OFF_WB1T + 262144;           // [512][512] bf16
static const size_t OFF_WA2T    = OFF_WINTRAT + 524288;        // [256][512] bf16
static const size_t OFF_WB2T    = OFF_WA2T + 262144;
static const size_t OFF_WINTERT = OFF_WB2T + 262144;           // [256][512] bf16

// canonical small-param offsets (bf16 elements within CANON)
#define CAN_BA1    0
#define CAN_BB1    256
#define CAN_WC1    512
#define CAN_BINTRA 768
#define CAN_BA2    1280
#define CAN_BB2    1536
#define CAN_WC2    1792
#define CAN_BINTER 2048
#define CAN_WCLS   2304
#define CAN_BCLS   2816

__device__ __forceinline__ int clip11(int c) { return c < 0 ? 0 : (c > 10 ? 10 : c); }

// NaN-PROPAGATING relu: keeps NaN visible (fmaxf would squash it)
__device__ __forceinline__ float relu_f(float v) { return v < 0.0f ? 0.0f : v; }

// read element i of a float-tensor input whose real dtype is f32 (fl=1) or bf16 (fl=0)
__device__ __forceinline__ float cvt(const void* p, int i, int fl) {
  return fl ? ((const float*)p)[i] : (float)((const bf16*)p)[i];
}

// monotone float->uint key for atomicMax (init 0 == "below all reals")
__device__ __forceinline__ unsigned fkey(float f) {
  unsigned u = __float_as_uint(f);
  return (u & 0x80000000u) ? ~u : (u | 0x80000000u);
}
__device__ __forceinline__ float key_to_f(unsigned k) {
  unsigned u = (k & 0x80000000u) ? (k & 0x7FFFFFFFu) : ~k;
  return __uint_as_float(u);
}

__device__ __forceinline__ void async16(const void* g, void* l) {
  __builtin_amdgcn_global_load_lds(
      (const __attribute__((address_space(1))) unsigned int*)g,
      (__attribute__((address_space(3))) unsigned int*)l, 16, 0, 0);
}

// stage ROWS x 64 bf16 tile, row-major [row][64], via global_load_lds width=16.
// LDS dest per instr = wave-uniform base + lane*16B -> covers 8 rows of [row][64].
template <int ROWS>
__device__ __forceinline__ void stage_async(const bf16* __restrict__ g, bf16* lds,
                                            int ldg, int lane, int wid) {
  const int row = lane >> 3;          // 8 rows per instruction
  const int ko  = (lane & 7) * 8;     // 8 bf16 per lane
  const int base = wid * (ROWS / 4);  // rows per wave
#pragma unroll
  for (int j = 0; j < ROWS / 4; j += 8)
    async16(g + (size_t)(base + j + row) * ldg + ko, lds + (base + j) * 64);
}

// ============ dtype detector: are float inputs f32 (flag=1) or bf16 (flag=0)? ============
__global__ void k_detect(const unsigned short* __restrict__ hh, int* __restrict__ flag) {
  const int lane = threadIdx.x;  // 64 lanes
  const unsigned short u = hh[lane * 2];
  const int e = (u >> 7) & 0xFF;
  int pl = (e > 96 && e < 140) ? 1 : 0;
#pragma unroll
  for (int off = 1; off < 64; off <<= 1) pl += __shfl_xor(pl, off, 64);
  if (lane == 0) *flag = (pl < 32) ? 1 : 0;
}

// ============ kernel 1: x = relu(h @ Wfuse + T[cid]) ============
// tile 128(m) x 128(n); 4 waves each own 32 rows x 128 cols (acc[2][8]).
// A-fragments read DIRECT from global (f32->bf16 cvt in regs); B staged async to LDS.
__global__ __launch_bounds__(256) void k_fuse(
    const void* __restrict__ h, const int* __restrict__ cids,
    const bf16* __restrict__ WfT, const float* __restrict__ Temb,
    const int* __restrict__ flag, bf16* __restrict__ x) {
  __shared__ __align__(16) bf16 Bs[128 * 64];
  const int tid = threadIdx.x, lane = tid & 63, wid = tid >> 6;
  const int quad = lane >> 4, l15 = lane & 15;
  const int m0 = blockIdx.y * 128, n0 = blockIdx.x * 128;
  const int fl = *flag;
  const float* hf = (const float*)h;
  const bf16*  hb = (const bf16*)h;

  f32x4 acc[2][8] = {};
  for (int k0 = 0; k0 < 512; k0 += 64) {
    stage_async<128>(WfT + (size_t)n0 * 512 + k0, Bs, 512, lane, wid);
    __syncthreads();
#pragma unroll
    for (int kk = 0; kk < 64; kk += 32) {
      // A fragments direct from global: row = m0 + wid*32 + tm*16 + l15, k = k0+kk+quad*8
      bf16x8 af[2];
#pragma unroll
      for (int tm = 0; tm < 2; ++tm) {
        const size_t roff = (size_t)(m0 + wid * 32 + tm * 16 + l15) * 512 + k0 + kk + quad * 8;
        if (fl) {
          fvec4 v0 = *(const fvec4*)(hf + roff);
          fvec4 v1 = *(const fvec4*)(hf + roff + 4);
          bf16x8 a;
          a[0] = (bf16)v0[0]; a[1] = (bf16)v0[1]; a[2] = (bf16)v0[2]; a[3] = (bf16)v0[3];
          a[4] = (bf16)v1[0]; a[5] = (bf16)v1[1]; a[6] = (bf16)v1[2]; a[7] = (bf16)v1[3];
          af[tm] = a;
        } else {
          af[tm] = *(const bf16x8*)(hb + roff);
        }
      }
      bf16x8 bfr[8];
#pragma unroll
      for (int t = 0; t < 8; ++t)
        bfr[t] = *(const bf16x8*)&Bs[(t * 16 + l15) * 64 + kk + quad * 8];
#pragma unroll
      for (int tm = 0; tm < 2; ++tm)
#pragma unroll
        for (int tn = 0; tn < 8; ++tn)
          acc[tm][tn] = __builtin_amdgcn_mfma_f32_16x16x32_bf16(af[tm], bfr[tn], acc[tm][tn], 0, 0, 0);
    }
    __syncthreads();
  }
#pragma unroll
  for (int tm = 0; tm < 2; ++tm) {
#pragma unroll
    for (int r = 0; r < 4; ++r) {
      const int m = m0 + wid * 32 + tm * 16 + quad * 4 + r;
      const int c = clip11(cids[m]);
      const float* Trow = Temb + c * 512;
#pragma unroll
      for (int tn = 0; tn < 8; ++tn) {
        const int nn = n0 + tn * 16 + l15;
        x[(size_t)m * 512 + nn] = (bf16)relu_f(acc[tm][tn][r] + Trow[nn]);
      }
    }
  }
}

// ============ kernel 2: A[m] += sum_n tanh(x@Wa1+ba1)*sigmoid(x@Wb1+bb1)*wc1 ============
// tile 128(m) x 128(n), waves 2x2 (64x64 each), dual acc, all operands async-staged
__global__ __launch_bounds__(256) void k_gate1(
    const bf16* __restrict__ x, const bf16* __restrict__ Wa1T, const bf16* __restrict__ Wb1T,
    const bf16* __restrict__ canon, float* __restrict__ Apart) {
  __shared__ __align__(16) bf16 As[128 * 64];
  __shared__ __align__(16) bf16 Ba[128 * 64];
  __shared__ __align__(16) bf16 Bb[128 * 64];
  const int tid = threadIdx.x, lane = tid & 63, wid = tid >> 6;
  const int quad = lane >> 4, l15 = lane & 15;
  const int wm = wid >> 1, wn = wid & 1;
  const int m0 = blockIdx.y * 128, n0 = blockIdx.x * 128;

  f32x4 aa[4][4] = {}, ag[4][4] = {};
  for (int k0 = 0; k0 < 512; k0 += 64) {
    stage_async<128>(x + (size_t)m0 * 512 + k0, As, 512, lane, wid);
    stage_async<128>(Wa1T + (size_t)n0 * 512 + k0, Ba, 512, lane, wid);
    stage_async<128>(Wb1T + (size_t)n0 * 512 + k0, Bb, 512, lane, wid);
    __syncthreads();
#pragma unroll
    for (int kk = 0; kk < 64; kk += 32) {
      bf16x8 af[4], bA[4], bB[4];
#pragma unroll
      for (int t = 0; t < 4; ++t)
        af[t] = *(const bf16x8*)&As[(wm * 64 + t * 16 + l15) * 64 + kk + quad * 8];
#pragma unroll
      for (int t = 0; t < 4; ++t) {
        bA[t] = *(const bf16x8*)&Ba[(wn * 64 + t * 16 + l15) * 64 + kk + quad * 8];
        bB[t] = *(const bf16x8*)&Bb[(wn * 64 + t * 16 + l15) * 64 + kk + quad * 8];
      }
#pragma unroll
      for (int tm = 0; tm < 4; ++tm)
#pragma unroll
        for (int tn = 0; tn < 4; ++tn) {
          aa[tm][tn] = __builtin_amdgcn_mfma_f32_16x16x32_bf16(af[tm], bA[tn], aa[tm][tn], 0, 0, 0);
          ag[tm][tn] = __builtin_amdgcn_mfma_f32_16x16x32_bf16(af[tm], bB[tn], ag[tm][tn], 0, 0, 0);
        }
    }
    __syncthreads();
  }
  float bav[4], bbv[4], wcv[4];
#pragma unroll
  for (int tn = 0; tn < 4; ++tn) {
    const int nn = n0 + wn * 64 + tn * 16 + l15;
    bav[tn] = (float)canon[CAN_BA1 + nn];
    bbv[tn] = (float)canon[CAN_BB1 + nn];
    wcv[tn] = (float)canon[CAN_WC1 + nn];
  }
#pragma unroll
  for (int tm = 0; tm < 4; ++tm) {
#pragma unroll
    for (int r = 0; r < 4; ++r) {
      float rs = 0.f;
#pragma unroll
      for (int tn = 0; tn < 4; ++tn) {
        const float av = aa[tm][tn][r] + bav[tn];
        const float gv = ag[tm][tn][r] + bbv[tn];
        rs += tanhf(av) * (1.f / (1.f + __expf(-gv))) * wcv[tn];
      }
      rs += __shfl_xor(rs, 1, 64);
      rs += __shfl_xor(rs, 2, 64);
      rs += __shfl_xor(rs, 4, 64);
      rs += __shfl_xor(rs, 8, 64);
      if (l15 == 0) atomicAdd(&Apart[m0 + wm * 64 + tm * 16 + quad * 4 + r], rs);
    }
  }
}

// ============ kernel 3a: per-segment max ============
__global__ __launch_bounds__(256) void k_segmax(
    const float* __restrict__ Apart, const int* __restrict__ cids, unsigned* __restrict__ gmax) {
  __shared__ unsigned sm[88];
  const int tid = threadIdx.x;
  if (tid < 88) sm[tid] = 0u;
  __syncthreads();
  const int base = blockIdx.x * 1024;
  const int b = blockIdx.x >> 4;  // 16 blocks per batch
#pragma unroll
  for (int it = 0; it < 4; ++it) {
    const int t = base + it * 256 + tid;
    atomicMax(&sm[b * 11 + clip11(cids[t])], fkey(Apart[t]));
  }
  __syncthreads();
  if (tid < 88) atomicMax(&gmax[tid], sm[tid]);
}

// ============ kernel 3b: per-segment sum of exp + counts ============
__global__ __launch_bounds__(256) void k_segsum(
    const float* __restrict__ Apart, const int* __restrict__ cids,
    const unsigned* __restrict__ gmax, float* __restrict__ denom, int* __restrict__ counts) {
  __shared__ float sd[88];
  __shared__ int sc[88];
  const int tid = threadIdx.x;
  if (tid < 88) { sd[tid] = 0.f; sc[tid] = 0; }
  __syncthreads();
  const int base = blockIdx.x * 1024;
  const int b = blockIdx.x >> 4;
#pragma unroll
  for (int it = 0; it < 4; ++it) {
    const int t = base + it * 256 + tid;
    const int seg = b * 11 + clip11(cids[t]);
    atomicAdd(&sd[seg], __expf(Apart[t] - key_to_f(gmax[seg])));
    atomicAdd(&sc[seg], 1);
  }
  __syncthreads();
  if (tid < 88) {
    atomicAdd(&denom[tid], sd[tid]);
    atomicAdd(&counts[tid], sc[tid]);
  }
}

// ============ kernel 3c: cfeat[seg] += w * x[token]  (LDS accumulation) ============
__global__ __launch_bounds__(256) void k_cfeat(
    const float* __restrict__ Apart, const int* __restrict__ cids,
    const unsigned* __restrict__ gmax, const float* __restrict__ denom,
    const bf16* __restrict__ x, float* __restrict__ cfeat) {
  __shared__ float accf[11 * 256];
  __shared__ float wbuf[1024];
  __shared__ unsigned char cbuf[1024];
  const int tid = threadIdx.x;
  const int base = blockIdx.x * 1024;
  const int b = blockIdx.x >> 4;
  const int nf0 = blockIdx.y * 256;
  for (int i = tid; i < 11 * 256; i += 256) accf[i] = 0.f;
#pragma unroll
  for (int it = 0; it < 4; ++it) {
    const int t = base + it * 256 + tid;
    const int c = clip11(cids[t]);
    const int seg = b * 11 + c;
    wbuf[it * 256 + tid] = __expf(Apart[t] - key_to_f(gmax[seg])) / denom[seg];
    cbuf[it * 256 + tid] = (unsigned char)c;
  }
  __syncthreads();
  const bf16* xp = x + (size_t)base * 512 + nf0 + tid;
#pragma unroll 4
  for (int i = 0; i < 1024; ++i) {
    const float w = wbuf[i];
    const int c = cbuf[i];
    accf[c * 256 + tid] += w * (float)xp[(size_t)i * 512];
  }
  __syncthreads();
  float* cf = cfeat + (size_t)b * 11 * 512 + nf0;
  for (int i = tid; i < 11 * 256; i += 256)
    atomicAdd(&cf[(i >> 8) * 512 + (i & 255)], accf[i]);
}

// ============ kernel 4a: cfeat2 = relu(cfeat @ Wintra + b_intra), 88 rows ============
__global__ __launch_bounds__(256) void k_intra(
    const float* __restrict__ cfeat, const bf16* __restrict__ WintraT,
    const bf16* __restrict__ canon, float* __restrict__ cfeat2) {
  __shared__ float row[512];
  const int r = blockIdx.x, tid = threadIdx.x;
  row[tid] = cfeat[(size_t)r * 512 + tid];
  row[tid + 256] = cfeat[(size_t)r * 512 + 256 + tid];
  __syncthreads();
#pragma unroll
  for (int hh = 0; hh < 2; ++hh) {
    const int n = hh * 256 + tid;
    float acc = (float)canon[CAN_BINTRA + n];
    const bf16* wp = WintraT + (size_t)n * 512;
    for (int k = 0; k < 512; k += 8) {
      bf16x8 wv = *(const bf16x8*)(wp + k);
#pragma unroll
      for (int j = 0; j < 8; ++j) acc += row[k + j] * (float)wv[j];
    }
    cfeat2[(size_t)r * 512 + n] = relu_f(acc);
  }
}

__device__ __forceinline__ float block_sum(float v, float* red, int tid) {
#pragma unroll
  for (int off = 32; off > 0; off >>= 1) v += __shfl_xor(v, off, 64);
  __syncthreads();
  if ((tid & 63) == 0) red[tid >> 6] = v;
  __syncthreads();
  return red[0] + red[1] + red[2] + red[3];
}

// ============ kernel 4b: inter-cluster attention + classifier, 1 block per batch ============
__global__ __launch_bounds__(256) void k_tail(
    const float* __restrict__ cfeat2, const int* __restrict__ counts,
    const bf16* __restrict__ Wa2T, const bf16* __restrict__ Wb2T,
    const bf16* __restrict__ WinterT, const bf16* __restrict__ canon,
    const int* __restrict__ flag, void* __restrict__ out) {
  const int b = blockIdx.x, tid = threadIdx.x;
  __shared__ float row[512];
  __shared__ float A2[11], Wsm[11];
  __shared__ float red[4];
  __shared__ float slide[512];
  __shared__ float hid[256];
  const float* cf = cfeat2 + (size_t)b * 11 * 512;

  for (int c = 0; c < 11; ++c) {
    row[tid] = cf[c * 512 + tid];
    row[tid + 256] = cf[c * 512 + 256 + tid];
    __syncthreads();
    float da = (float)canon[CAN_BA2 + tid], dg = (float)canon[CAN_BB2 + tid];
    const bf16* wa = Wa2T + (size_t)tid * 512;
    const bf16* wb = Wb2T + (size_t)tid * 512;
    for (int k = 0; k < 512; k += 8) {
      bf16x8 av = *(const bf16x8*)(wa + k);
      bf16x8 gv = *(const bf16x8*)(wb + k);
#pragma unroll
      for (int j = 0; j < 8; ++j) {
        const float rv = row[k + j];
        da += rv * (float)av[j];
        dg += rv * (float)gv[j];
      }
    }
    const float contrib = tanhf(da) * (1.f / (1.f + __expf(-dg))) * (float)canon[CAN_WC2 + tid];
    const float tot = block_sum(contrib, red, tid);
    if (tid == 0) A2[c] = tot;
    __syncthreads();
  }
  if (tid == 0) {  // masked softmax over 11 clusters (bc2 cancels)
    float mx = -1e30f;
    for (int c = 0; c < 11; ++c)
      if (counts[b * 11 + c] > 0 && A2[c] > mx) mx = A2[c];
    float s = 0.f;
    for (int c = 0; c < 11; ++c) {
      const float e = (counts[b * 11 + c] > 0) ? __expf(A2[c] - mx) : 0.f;
      Wsm[c] = e; s += e;
    }
    for (int c = 0; c < 11; ++c) Wsm[c] /= s;
  }
  __syncthreads();
  float s0 = 0.f, s1 = 0.f;
  for (int c = 0; c < 11; ++c) {
    const float w = Wsm[c];
    s0 += w * cf[c * 512 + tid];
    s1 += w * cf[c * 512 + 256 + tid];
  }
  slide[tid] = s0; slide[tid + 256] = s1;
  __syncthreads();
  {
    float acc = (float)canon[CAN_BINTER + tid];
    const bf16* wp = WinterT + (size_t)tid * 512;
    for (int k = 0; k < 512; k += 8) {
      bf16x8 wv = *(const bf16x8*)(wp + k);
#pragma unroll
      for (int j = 0; j < 8; ++j) acc += slide[k + j] * (float)wv[j];
    }
    hid[tid] = relu_f(acc);
  }
  __syncthreads();
  const float p0 = hid[tid] * (float)canon[CAN_WCLS + tid * 2 + 0];
  const float p1 = hid[tid] * (float)canon[CAN_WCLS + tid * 2 + 1];
  const float t0 = block_sum(p0, red, tid);
  const float t1 = block_sum(p1, red, tid);
  if (tid == 0) {
    const float o0 = t0 + (float)canon[CAN_BCLS + 0];
    const float o1 = t1 + (float)canon[CAN_BCLS + 1];
    if (*flag) {
      ((float*)out)[b * 2 + 0] = o0;
      ((float*)out)[b * 2 + 1] = o1;
    } else {
      ((bf16*)out)[b * 2 + 0] = (bf16)o0;
      ((bf16*)out)[b * 2 + 1] = (bf16)o1;
    }
  }
}

// ============ prep: dtype-adaptive weight transposes + canonical params + emb-tail ============
__global__ __launch_bounds__(256) void k_prep(
    const void* __restrict__ Wf, const void* __restrict__ bfuse, const void* __restrict__ emb,
    const void* __restrict__ Wa1, const void* __restrict__ Wb1, const void* __restrict__ Wintra,
    const void* __restrict__ Wa2, const void* __restrict__ Wb2, const void* __restrict__ Winter,
    const void* __restrict__ ba1, const void* __restrict__ bb1, const void* __restrict__ wc1,
    const void* __restrict__ bintra, const void* __restrict__ ba2, const void* __restrict__ bb2,
    const void* __restrict__ wc2, const void* __restrict__ binter, const void* __restrict__ Wcls,
    const void* __restrict__ bcls, const int* __restrict__ flag,
    bf16* __restrict__ WfT, bf16* __restrict__ Wa1T, bf16* __restrict__ Wb1T,
    bf16* __restrict__ WintraT, bf16* __restrict__ Wa2T, bf16* __restrict__ Wb2T,
    bf16* __restrict__ WinterT, float* __restrict__ Temb, bf16* __restrict__ canon) {
  const int fl = *flag;
  int id = blockIdx.x * 256 + threadIdx.x;
  if (id < 262144) { WfT[id] = (bf16)cvt(Wf, (id & 511) * 512 + (id >> 9), fl); return; }
  id -= 262144;
  if (id < 131072) { Wa1T[id] = (bf16)cvt(Wa1, (id & 511) * 256 + (id >> 9), fl); return; }
  id -= 131072;
  if (id < 131072) { Wb1T[id] = (bf16)cvt(Wb1, (id & 511) * 256 + (id >> 9), fl); return; }
  id -= 131072;
  if (id < 262144) { WintraT[id] = (bf16)cvt(Wintra, (id & 511) * 512 + (id >> 9), fl); return; }
  id -= 262144;
  if (id < 131072) { Wa2T[id] = (bf16)cvt(Wa2, (id & 511) * 256 + (id >> 9), fl); return; }
  id -= 131072;
  if (id < 131072) { Wb2T[id] = (bf16)cvt(Wb2, (id & 511) * 256 + (id >> 9), fl); return; }
  id -= 131072;
  if (id < 131072) { WinterT[id] = (bf16)cvt(Winter, (id & 511) * 256 + (id >> 9), fl); return; }
  id -= 131072;
  if (id < 5632) {
    const int c = id >> 9, n = id & 511;
    float s = cvt(bfuse, n, fl);
#pragma unroll
    for (int j = 0; j < 8; ++j) s += cvt(emb, c * 8 + j, fl) * cvt(Wf, (512 + j) * 512 + n, fl);
    Temb[id] = s;
    return;
  }
  id -= 5632;
  if (id < 4096) {
    bf16 v = (bf16)0.0f;
    if (id < 256)        v = (bf16)cvt(ba1, id, fl);
    else if (id < 512)   v = (bf16)cvt(bb1, id - 256, fl);
    else if (id < 768)   v = (bf16)cvt(wc1, id - 512, fl);
    else if (id < 1280)  v = (bf16)cvt(bintra, id - 768, fl);
    else if (id < 1536)  v = (bf16)cvt(ba2, id - 1280, fl);
    else if (id < 1792)  v = (bf16)cvt(bb2, id - 1536, fl);
    else if (id < 2048)  v = (bf16)cvt(wc2, id - 1792, fl);
    else if (id < 2304)  v = (bf16)cvt(binter, id - 2048, fl);
    else if (id < 2816)  v = (bf16)cvt(Wcls, id - 2304, fl);
    else if (id < 2818)  v = (bf16)cvt(bcls, id - 2816, fl);
    canon[id] = v;
  }
}

extern "C" void kernel_launch(void* const* d_in, const int* in_sizes, int n_in,
                              void* d_out, int out_size, void* d_ws, size_t ws_size,
                              hipStream_t stream) {
  (void)in_sizes; (void)n_in; (void)out_size; (void)ws_size;
  const void* h      = d_in[0];
  const int*  cids   = (const int*)d_in[1];
  const void* emb    = d_in[2];
  const void* Wf     = d_in[3];
  const void* bfuse  = d_in[4];
  const void* Wa1    = d_in[5];
  const void* ba1    = d_in[6];
  const void* Wb1    = d_in[7];
  const void* bb1    = d_in[8];
  const void* wc1    = d_in[9];
  // d_in[10] = bc1: cancels in segment softmax
  const void* Wintra = d_in[11];
  const void* bintra = d_in[12];
  const void* Wa2    = d_in[13];
  const void* ba2    = d_in[14];
  const void* Wb2    = d_in[15];
  const void* bb2    = d_in[16];
  const void* wc2    = d_in[17];
  // d_in[18] = bc2: cancels in inter softmax
  const void* Winter = d_in[19];
  const void* binter = d_in[20];
  const void* Wcls   = d_in[21];
  const void* bcls   = d_in[22];

  char* ws = (char*)d_ws;
  float*    Apart   = (float*)(ws + OFF_A);
  unsigned* gmax    = (unsigned*)(ws + OFF_SEGMAX);
  float*    denom   = (float*)(ws + OFF_DENOM);
  int*      counts  = (int*)(ws + OFF_CNT);
  float*    cfeat   = (float*)(ws + OFF_CFEAT);
  float*    cfeat2  = (float*)(ws + OFF_CFEAT2);
  int*      flag    = (int*)(ws + OFF_FLAG);
  bf16*     canon   = (bf16*)(ws + OFF_CANON);
  float*    Temb    = (float*)(ws + OFF_TEMB);
  bf16*     x       = (bf16*)(ws + OFF_X);
  bf16*     WfT     = (bf16*)(ws + OFF_WFT);
  bf16*     Wa1T    = (bf16*)(ws + OFF_WA1T);
  bf16*     Wb1T    = (bf16*)(ws + OFF_WB1T);
  bf16*     WintraT = (bf16*)(ws + OFF_WINTRAT);
  bf16*     Wa2T    = (bf16*)(ws + OFF_WA2T);
  bf16*     Wb2T    = (bf16*)(ws + OFF_WB2T);
  bf16*     WinterT = (bf16*)(ws + OFF_WINTERT);

  hipMemsetAsync(d_ws, 0, ZERO_BYTES, stream);
  k_detect<<<1, 64, 0, stream>>>((const unsigned short*)h, flag);
  k_prep<<<4646, 256, 0, stream>>>(Wf, bfuse, emb, Wa1, Wb1, Wintra, Wa2, Wb2, Winter,
                                   ba1, bb1, wc1, bintra, ba2, bb2, wc2, binter, Wcls, bcls,
                                   flag, WfT, Wa1T, Wb1T, WintraT, Wa2T, Wb2T, WinterT,
                                   Temb, canon);
  k_fuse<<<dim3(4, 1024), 256, 0, stream>>>(h, cids, WfT, Temb, flag, x);
  k_gate1<<<dim3(2, 1024), 256, 0, stream>>>(x, Wa1T, Wb1T, canon, Apart);
  k_segmax<<<128, 256, 0, stream>>>(Apart, cids, gmax);
  k_segsum<<<128, 256, 0, stream>>>(Apart, cids, gmax, denom, counts);
  k_cfeat<<<dim3(128, 2), 256, 0, stream>>>(Apart, cids, gmax, denom, x, cfeat);
  k_intra<<<88, 256, 0, stream>>>(cfeat, WintraT, canon, cfeat2);
  k_tail<<<8, 256, 0, stream>>>(cfeat2, counts, Wa2T, Wb2T, WinterT, canon, flag, d_out);
}

// Round 5
// 942.829 us; speedup vs baseline: 1.3477x; 1.2509x over previous
//
#include <hip/hip_runtime.h>
#include <stdint.h>

typedef __bf16 bf16;
typedef __bf16 bf16x8 __attribute__((ext_vector_type(8)));
typedef __bf16 bf16x4 __attribute__((ext_vector_type(4)));
typedef __bf16 bf16x2 __attribute__((ext_vector_type(2)));
typedef float  f32x4  __attribute__((ext_vector_type(4)));
typedef float  fvec4  __attribute__((ext_vector_type(4)));

// ---------------- workspace layout (bytes) ----------------
static const size_t OFF_A       = 0;         // 131072 f32 (per-token attn logit)
static const size_t OFF_SEGMAX  = 524288;    // 88 u32 (ordered-key max)
static const size_t OFF_DENOM   = 524800;    // 88 f32
static const size_t OFF_CNT     = 525312;    // 88 i32
static const size_t OFF_CFEAT   = 525824;    // 88*512 f32
static const size_t OFF_CFEAT2  = 706048;    // 88*512 f32
static const size_t ZERO_BYTES  = 886272;    // everything above zeroed each call
static const size_t OFF_FLAG    = 886272;    // 64 B (dtype flag)
static const size_t OFF_CANON   = 886336;    // 4096 bf16 canonical small params
static const size_t OFF_TEMB    = 894528;    // [11][512] f32 (emb tail + b_fuse)
static const size_t OFF_X       = 917056;    // 131072*512 bf16 = 128 MiB
static const size_t OFF_WFT     = OFF_X + (size_t)134217728;   // [512][512] bf16
static const size_t OFF_WGT     = OFF_WFT + 524288;            // [512][512] bf16 (Wa1/Wb1 col-interleaved)
static const size_t OFF_WINTRAT = OFF_WGT + 524288;            // [512][512] bf16
static const size_t OFF_WA2T    = OFF_WINTRAT + 524288;        // [256][512] bf16
static const size_t OFF_WB2T    = OFF_WA2T + 262144;
static const size_t OFF_WINTERT = OFF_WB2T + 262144;           // [256][512] bf16

// canonical small-param offsets (bf16 elements within CANON)
#define CAN_BA1    0
#define CAN_BB1    256
#define CAN_WC1    512
#define CAN_BINTRA 768
#define CAN_BA2    1280
#define CAN_BB2    1536
#define CAN_WC2    1792
#define CAN_BINTER 2048
#define CAN_WCLS   2304
#define CAN_BCLS   2816

__device__ __forceinline__ int clip11(int c) { return c < 0 ? 0 : (c > 10 ? 10 : c); }

// NaN-PROPAGATING relu
__device__ __forceinline__ float relu_f(float v) { return v < 0.0f ? 0.0f : v; }

__device__ __forceinline__ float cvt(const void* p, int i, int fl) {
  return fl ? ((const float*)p)[i] : (float)((const bf16*)p)[i];
}

__device__ __forceinline__ unsigned fkey(float f) {
  unsigned u = __float_as_uint(f);
  return (u & 0x80000000u) ? ~u : (u | 0x80000000u);
}
__device__ __forceinline__ float key_to_f(unsigned k) {
  unsigned u = (k & 0x80000000u) ? (k & 0x7FFFFFFFu) : ~k;
  return __uint_as_float(u);
}

__device__ __forceinline__ void async16(const void* g, void* l) {
  __builtin_amdgcn_global_load_lds(
      (const __attribute__((address_space(1))) unsigned int*)g,
      (__attribute__((address_space(3))) unsigned int*)l, 16, 0, 0);
}

// stage ROWS x 64 bf16 tile, row-major [row][64], via global_load_lds width=16.
template <int ROWS>
__device__ __forceinline__ void stage_async(const bf16* __restrict__ g, bf16* lds,
                                            int ldg, int lane, int wid) {
  const int row = lane >> 3;          // 8 rows per instruction
  const int ko  = (lane & 7) * 8;     // 8 bf16 per lane
  const int base = wid * (ROWS / 4);  // rows per wave
#pragma unroll
  for (int j = 0; j < ROWS / 4; j += 8)
    async16(g + (size_t)(base + j + row) * ldg + ko, lds + (base + j) * 64);
}

// stage 64x64 tile from f32 source -> bf16 LDS (A operand of k_fuse), 256 threads
__device__ __forceinline__ void stage_a_f32(const float* __restrict__ g, bf16* lds,
                                            int ldg, int tid) {
  const int row = tid >> 2;          // 64 rows, 4 threads/row
  const int co  = (tid & 3) * 16;    // 16 f32 per thread
  const float* gp = g + (size_t)row * ldg + co;
  fvec4 v0 = *(const fvec4*)(gp);
  fvec4 v1 = *(const fvec4*)(gp + 4);
  fvec4 v2 = *(const fvec4*)(gp + 8);
  fvec4 v3 = *(const fvec4*)(gp + 12);
  bf16x8 b0, b1;
  b0[0]=(bf16)v0[0]; b0[1]=(bf16)v0[1]; b0[2]=(bf16)v0[2]; b0[3]=(bf16)v0[3];
  b0[4]=(bf16)v1[0]; b0[5]=(bf16)v1[1]; b0[6]=(bf16)v1[2]; b0[7]=(bf16)v1[3];
  b1[0]=(bf16)v2[0]; b1[1]=(bf16)v2[1]; b1[2]=(bf16)v2[2]; b1[3]=(bf16)v2[3];
  b1[4]=(bf16)v3[0]; b1[5]=(bf16)v3[1]; b1[6]=(bf16)v3[2]; b1[7]=(bf16)v3[3];
  *(bf16x8*)(lds + row * 64 + co) = b0;
  *(bf16x8*)(lds + row * 64 + co + 8) = b1;
}

// ============ dtype detector ============
__global__ void k_detect(const unsigned short* __restrict__ hh, int* __restrict__ flag) {
  const int lane = threadIdx.x;  // 64 lanes
  const unsigned short u = hh[lane * 2];
  const int e = (u >> 7) & 0xFF;
  int pl = (e > 96 && e < 140) ? 1 : 0;
#pragma unroll
  for (int off = 1; off < 64; off <<= 1) pl += __shfl_xor(pl, off, 64);
  if (lane == 0) *flag = (pl < 32) ? 1 : 0;
}

// ============ kernel 1: x = relu(h @ Wfuse + T[cid]) ============
// block = 64 tokens x full N=512. 4 waves: wave tile 64m x 128n (acc[4][8]).
// h rows read exactly ONCE chip-wide (f32 cvt in staging); B via async16.
__global__ __launch_bounds__(256, 2) void k_fuse(
    const void* __restrict__ h, const int* __restrict__ cids,
    const bf16* __restrict__ WfT, const float* __restrict__ Temb,
    const int* __restrict__ flag, bf16* __restrict__ x) {
  __shared__ __align__(16) bf16 As[64 * 64];     // 8 KB
  __shared__ __align__(16) bf16 Bs[512 * 64];    // 64 KB
  const int tid = threadIdx.x, lane = tid & 63, wid = tid >> 6;
  const int quad = lane >> 4, l15 = lane & 15;
  const int m0 = blockIdx.x * 64;
  const int fl = *flag;

  f32x4 acc[4][8] = {};
  for (int k0 = 0; k0 < 512; k0 += 64) {
    if (fl) stage_a_f32((const float*)h + (size_t)m0 * 512 + k0, As, 512, tid);
    else    stage_async<64>((const bf16*)h + (size_t)m0 * 512 + k0, As, 512, lane, wid);
    stage_async<512>(WfT + k0, Bs, 512, lane, wid);
    __syncthreads();
#pragma unroll
    for (int kk = 0; kk < 64; kk += 32) {
      bf16x8 af[4], bfr[8];
#pragma unroll
      for (int t = 0; t < 4; ++t)
        af[t] = *(const bf16x8*)&As[(t * 16 + l15) * 64 + kk + quad * 8];
#pragma unroll
      for (int t = 0; t < 8; ++t)
        bfr[t] = *(const bf16x8*)&Bs[(wid * 128 + t * 16 + l15) * 64 + kk + quad * 8];
#pragma unroll
      for (int tm = 0; tm < 4; ++tm)
#pragma unroll
        for (int tn = 0; tn < 8; ++tn)
          acc[tm][tn] = __builtin_amdgcn_mfma_f32_16x16x32_bf16(af[tm], bfr[tn], acc[tm][tn], 0, 0, 0);
    }
    __syncthreads();
  }
#pragma unroll
  for (int tm = 0; tm < 4; ++tm) {
#pragma unroll
    for (int r = 0; r < 4; ++r) {
      const int m = m0 + tm * 16 + quad * 4 + r;
      const int c = clip11(cids[m]);
      const float* Trow = Temb + c * 512;
#pragma unroll
      for (int tn = 0; tn < 8; ++tn) {
        const int nn = wid * 128 + tn * 16 + l15;
        x[(size_t)m * 512 + nn] = (bf16)relu_f(acc[tm][tn][r] + Trow[nn]);
      }
    }
  }
}

// ============ kernel 2: per-token gate logit, fully in-block ============
// WgT: gate cols interleaved (even=tanh-side dim d, odd=sigmoid-side dim d).
// block = 64 tokens x 512 gate-cols; pairs combined via shfl_xor(lane^1).
__global__ __launch_bounds__(256, 2) void k_gate1(
    const bf16* __restrict__ x, const bf16* __restrict__ WgT,
    const bf16* __restrict__ canon, float* __restrict__ Apart) {
  __shared__ __align__(16) bf16 As[64 * 64];     // 8 KB
  __shared__ __align__(16) bf16 Bs[512 * 64];    // 64 KB
  __shared__ float tok[64];
  const int tid = threadIdx.x, lane = tid & 63, wid = tid >> 6;
  const int quad = lane >> 4, l15 = lane & 15;
  const int m0 = blockIdx.x * 64;

  f32x4 acc[4][8] = {};
  for (int k0 = 0; k0 < 512; k0 += 64) {
    stage_async<64>(x + (size_t)m0 * 512 + k0, As, 512, lane, wid);
    stage_async<512>(WgT + k0, Bs, 512, lane, wid);
    __syncthreads();
#pragma unroll
    for (int kk = 0; kk < 64; kk += 32) {
      bf16x8 af[4], bfr[8];
#pragma unroll
      for (int t = 0; t < 4; ++t)
        af[t] = *(const bf16x8*)&As[(t * 16 + l15) * 64 + kk + quad * 8];
#pragma unroll
      for (int t = 0; t < 8; ++t)
        bfr[t] = *(const bf16x8*)&Bs[(wid * 128 + t * 16 + l15) * 64 + kk + quad * 8];
#pragma unroll
      for (int tm = 0; tm < 4; ++tm)
#pragma unroll
        for (int tn = 0; tn < 8; ++tn)
          acc[tm][tn] = __builtin_amdgcn_mfma_f32_16x16x32_bf16(af[tm], bfr[tn], acc[tm][tn], 0, 0, 0);
    }
    __syncthreads();
  }
  if (tid < 64) tok[tid] = 0.f;
  __syncthreads();
  // bias/wc per tn (valid for even lanes): d = wid*64 + tn*8 + l15/2
  float bav[8], bbv[8], wcv[8];
#pragma unroll
  for (int tn = 0; tn < 8; ++tn) {
    const int d = wid * 64 + tn * 8 + (l15 >> 1);
    bav[tn] = (float)canon[CAN_BA1 + d];
    bbv[tn] = (float)canon[CAN_BB1 + d];
    wcv[tn] = (float)canon[CAN_WC1 + d];
  }
  const int even = ((l15 & 1) == 0);
#pragma unroll
  for (int tm = 0; tm < 4; ++tm) {
#pragma unroll
    for (int r = 0; r < 4; ++r) {
      float rs = 0.f;
#pragma unroll
      for (int tn = 0; tn < 8; ++tn) {
        const float v = acc[tm][tn][r];
        const float pg = __shfl_xor(v, 1, 64);  // partner (odd lane holds sigmoid side)
        if (even) {
          const float a = v + bav[tn];
          const float g = pg + bbv[tn];
          rs += tanhf(a) * (1.f / (1.f + __expf(-g))) * wcv[tn];
        }
      }
      rs += __shfl_xor(rs, 1, 64);
      rs += __shfl_xor(rs, 2, 64);
      rs += __shfl_xor(rs, 4, 64);
      rs += __shfl_xor(rs, 8, 64);
      if (l15 == 0) atomicAdd(&tok[tm * 16 + quad * 4 + r], rs);
    }
  }
  __syncthreads();
  if (tid < 64) Apart[m0 + tid] = tok[tid];
}

// ============ kernel 3a: per-segment max ============
__global__ __launch_bounds__(256) void k_segmax(
    const float* __restrict__ Apart, const int* __restrict__ cids, unsigned* __restrict__ gmax) {
  __shared__ unsigned sm[88];
  const int tid = threadIdx.x;
  if (tid < 88) sm[tid] = 0u;
  __syncthreads();
  const int base = blockIdx.x * 1024;
  const int b = blockIdx.x >> 4;
#pragma unroll
  for (int it = 0; it < 4; ++it) {
    const int t = base + it * 256 + tid;
    atomicMax(&sm[b * 11 + clip11(cids[t])], fkey(Apart[t]));
  }
  __syncthreads();
  if (tid < 88) atomicMax(&gmax[tid], sm[tid]);
}

// ============ kernel 3b: per-segment sum of exp + counts ============
__global__ __launch_bounds__(256) void k_segsum(
    const float* __restrict__ Apart, const int* __restrict__ cids,
    const unsigned* __restrict__ gmax, float* __restrict__ denom, int* __restrict__ counts) {
  __shared__ float sd[88];
  __shared__ int sc[88];
  const int tid = threadIdx.x;
  if (tid < 88) { sd[tid] = 0.f; sc[tid] = 0; }
  __syncthreads();
  const int base = blockIdx.x * 1024;
  const int b = blockIdx.x >> 4;
#pragma unroll
  for (int it = 0; it < 4; ++it) {
    const int t = base + it * 256 + tid;
    const int seg = b * 11 + clip11(cids[t]);
    atomicAdd(&sd[seg], __expf(Apart[t] - key_to_f(gmax[seg])));
    atomicAdd(&sc[seg], 1);
  }
  __syncthreads();
  if (tid < 88) {
    atomicAdd(&denom[tid], sd[tid]);
    atomicAdd(&counts[tid], sc[tid]);
  }
}

// ============ kernel 3c: cfeat[seg] += w * x[token] (full 512 cols, bf16x2) ============
__global__ __launch_bounds__(256) void k_cfeat(
    const float* __restrict__ Apart, const int* __restrict__ cids,
    const unsigned* __restrict__ gmax, const float* __restrict__ denom,
    const bf16* __restrict__ x, float* __restrict__ cfeat) {
  __shared__ float accf[11 * 512];      // 22.5 KB
  __shared__ float wbuf[512];
  __shared__ unsigned char cbuf[512];
  const int tid = threadIdx.x;
  const int base = blockIdx.x * 512;    // 256 blocks x 512 tokens
  const int b = blockIdx.x >> 5;        // 32 blocks per batch
  for (int i = tid; i < 11 * 512; i += 256) accf[i] = 0.f;
#pragma unroll
  for (int it = 0; it < 2; ++it) {
    const int t = base + it * 256 + tid;
    const int c = clip11(cids[t]);
    const int seg = b * 11 + c;
    wbuf[it * 256 + tid] = __expf(Apart[t] - key_to_f(gmax[seg])) / denom[seg];
    cbuf[it * 256 + tid] = (unsigned char)c;
  }
  __syncthreads();
  const bf16* xp = x + (size_t)base * 512 + tid * 2;
#pragma unroll 4
  for (int i = 0; i < 512; ++i) {
    const float w = wbuf[i];
    const int c = cbuf[i];
    bf16x2 v = *(const bf16x2*)(xp + (size_t)i * 512);
    accf[c * 512 + tid * 2]     += w * (float)v[0];
    accf[c * 512 + tid * 2 + 1] += w * (float)v[1];
  }
  __syncthreads();
  float* cf = cfeat + (size_t)b * 11 * 512;
  for (int i = tid; i < 11 * 512; i += 256)
    atomicAdd(&cf[i], accf[i]);
}

// ============ kernel 4a: cfeat2 = relu(cfeat @ Wintra + b_intra), 88 rows ============
__global__ __launch_bounds__(256) void k_intra(
    const float* __restrict__ cfeat, const bf16* __restrict__ WintraT,
    const bf16* __restrict__ canon, float* __restrict__ cfeat2) {
  __shared__ float row[512];
  const int r = blockIdx.x, tid = threadIdx.x;
  row[tid] = cfeat[(size_t)r * 512 + tid];
  row[tid + 256] = cfeat[(size_t)r * 512 + 256 + tid];
  __syncthreads();
#pragma unroll
  for (int hh = 0; hh < 2; ++hh) {
    const int n = hh * 256 + tid;
    float acc = (float)canon[CAN_BINTRA + n];
    const bf16* wp = WintraT + (size_t)n * 512;
    for (int k = 0; k < 512; k += 8) {
      bf16x8 wv = *(const bf16x8*)(wp + k);
#pragma unroll
      for (int j = 0; j < 8; ++j) acc += row[k + j] * (float)wv[j];
    }
    cfeat2[(size_t)r * 512 + n] = relu_f(acc);
  }
}

__device__ __forceinline__ float block_sum(float v, float* red, int tid) {
#pragma unroll
  for (int off = 32; off > 0; off >>= 1) v += __shfl_xor(v, off, 64);
  __syncthreads();
  if ((tid & 63) == 0) red[tid >> 6] = v;
  __syncthreads();
  return red[0] + red[1] + red[2] + red[3];
}

// ============ kernel 4b: inter-cluster attention + classifier ============
__global__ __launch_bounds__(256) void k_tail(
    const float* __restrict__ cfeat2, const int* __restrict__ counts,
    const bf16* __restrict__ Wa2T, const bf16* __restrict__ Wb2T,
    const bf16* __restrict__ WinterT, const bf16* __restrict__ canon,
    const int* __restrict__ flag, void* __restrict__ out) {
  const int b = blockIdx.x, tid = threadIdx.x;
  __shared__ float row[512];
  __shared__ float A2[11], Wsm[11];
  __shared__ float red[4];
  __shared__ float slide[512];
  __shared__ float hid[256];
  const float* cf = cfeat2 + (size_t)b * 11 * 512;

  for (int c = 0; c < 11; ++c) {
    row[tid] = cf[c * 512 + tid];
    row[tid + 256] = cf[c * 512 + 256 + tid];
    __syncthreads();
    float da = (float)canon[CAN_BA2 + tid], dg = (float)canon[CAN_BB2 + tid];
    const bf16* wa = Wa2T + (size_t)tid * 512;
    const bf16* wb = Wb2T + (size_t)tid * 512;
    for (int k = 0; k < 512; k += 8) {
      bf16x8 av = *(const bf16x8*)(wa + k);
      bf16x8 gv = *(const bf16x8*)(wb + k);
#pragma unroll
      for (int j = 0; j < 8; ++j) {
        const float rv = row[k + j];
        da += rv * (float)av[j];
        dg += rv * (float)gv[j];
      }
    }
    const float contrib = tanhf(da) * (1.f / (1.f + __expf(-dg))) * (float)canon[CAN_WC2 + tid];
    const float tot = block_sum(contrib, red, tid);
    if (tid == 0) A2[c] = tot;
    __syncthreads();
  }
  if (tid == 0) {
    float mx = -1e30f;
    for (int c = 0; c < 11; ++c)
      if (counts[b * 11 + c] > 0 && A2[c] > mx) mx = A2[c];
    float s = 0.f;
    for (int c = 0; c < 11; ++c) {
      const float e = (counts[b * 11 + c] > 0) ? __expf(A2[c] - mx) : 0.f;
      Wsm[c] = e; s += e;
    }
    for (int c = 0; c < 11; ++c) Wsm[c] /= s;
  }
  __syncthreads();
  float s0 = 0.f, s1 = 0.f;
  for (int c = 0; c < 11; ++c) {
    const float w = Wsm[c];
    s0 += w * cf[c * 512 + tid];
    s1 += w * cf[c * 512 + 256 + tid];
  }
  slide[tid] = s0; slide[tid + 256] = s1;
  __syncthreads();
  {
    float acc = (float)canon[CAN_BINTER + tid];
    const bf16* wp = WinterT + (size_t)tid * 512;
    for (int k = 0; k < 512; k += 8) {
      bf16x8 wv = *(const bf16x8*)(wp + k);
#pragma unroll
      for (int j = 0; j < 8; ++j) acc += slide[k + j] * (float)wv[j];
    }
    hid[tid] = relu_f(acc);
  }
  __syncthreads();
  const float p0 = hid[tid] * (float)canon[CAN_WCLS + tid * 2 + 0];
  const float p1 = hid[tid] * (float)canon[CAN_WCLS + tid * 2 + 1];
  const float t0 = block_sum(p0, red, tid);
  const float t1 = block_sum(p1, red, tid);
  if (tid == 0) {
    const float o0 = t0 + (float)canon[CAN_BCLS + 0];
    const float o1 = t1 + (float)canon[CAN_BCLS + 1];
    if (*flag) {
      ((float*)out)[b * 2 + 0] = o0;
      ((float*)out)[b * 2 + 1] = o1;
    } else {
      ((bf16*)out)[b * 2 + 0] = (bf16)o0;
      ((bf16*)out)[b * 2 + 1] = (bf16)o1;
    }
  }
}

// ============ prep: transposes + interleaved gate weight + canon + emb-tail ============
__global__ __launch_bounds__(256) void k_prep(
    const void* __restrict__ Wf, const void* __restrict__ bfuse, const void* __restrict__ emb,
    const void* __restrict__ Wa1, const void* __restrict__ Wb1, const void* __restrict__ Wintra,
    const void* __restrict__ Wa2, const void* __restrict__ Wb2, const void* __restrict__ Winter,
    const void* __restrict__ ba1, const void* __restrict__ bb1, const void* __restrict__ wc1,
    const void* __restrict__ bintra, const void* __restrict__ ba2, const void* __restrict__ bb2,
    const void* __restrict__ wc2, const void* __restrict__ binter, const void* __restrict__ Wcls,
    const void* __restrict__ bcls, const int* __restrict__ flag,
    bf16* __restrict__ WfT, bf16* __restrict__ WgT,
    bf16* __restrict__ WintraT, bf16* __restrict__ Wa2T, bf16* __restrict__ Wb2T,
    bf16* __restrict__ WinterT, float* __restrict__ Temb, bf16* __restrict__ canon) {
  const int fl = *flag;
  int id = blockIdx.x * 256 + threadIdx.x;
  if (id < 262144) { WfT[id] = (bf16)cvt(Wf, (id & 511) * 512 + (id >> 9), fl); return; }
  id -= 262144;
  if (id < 262144) {  // WgT row r: even -> Wa1 dim r/2, odd -> Wb1 dim r/2
    const int r = id >> 9, k = id & 511, d = r >> 1;
    WgT[id] = (bf16)cvt((r & 1) ? Wb1 : Wa1, k * 256 + d, fl);
    return;
  }
  id -= 262144;
  if (id < 262144) { WintraT[id] = (bf16)cvt(Wintra, (id & 511) * 512 + (id >> 9), fl); return; }
  id -= 262144;
  if (id < 131072) { Wa2T[id] = (bf16)cvt(Wa2, (id & 511) * 256 + (id >> 9), fl); return; }
  id -= 131072;
  if (id < 131072) { Wb2T[id] = (bf16)cvt(Wb2, (id & 511) * 256 + (id >> 9), fl); return; }
  id -= 131072;
  if (id < 131072) { WinterT[id] = (bf16)cvt(Winter, (id & 511) * 256 + (id >> 9), fl); return; }
  id -= 131072;
  if (id < 5632) {
    const int c = id >> 9, n = id & 511;
    float s = cvt(bfuse, n, fl);
#pragma unroll
    for (int j = 0; j < 8; ++j) s += cvt(emb, c * 8 + j, fl) * cvt(Wf, (512 + j) * 512 + n, fl);
    Temb[id] = s;
    return;
  }
  id -= 5632;
  if (id < 4096) {
    bf16 v = (bf16)0.0f;
    if (id < 256)        v = (bf16)cvt(ba1, id, fl);
    else if (id < 512)   v = (bf16)cvt(bb1, id - 256, fl);
    else if (id < 768)   v = (bf16)cvt(wc1, id - 512, fl);
    else if (id < 1280)  v = (bf16)cvt(bintra, id - 768, fl);
    else if (id < 1536)  v = (bf16)cvt(ba2, id - 1280, fl);
    else if (id < 1792)  v = (bf16)cvt(bb2, id - 1536, fl);
    else if (id < 2048)  v = (bf16)cvt(wc2, id - 1792, fl);
    else if (id < 2304)  v = (bf16)cvt(binter, id - 2048, fl);
    else if (id < 2816)  v = (bf16)cvt(Wcls, id - 2304, fl);
    else if (id < 2818)  v = (bf16)cvt(bcls, id - 2816, fl);
    canon[id] = v;
  }
}

extern "C" void kernel_launch(void* const* d_in, const int* in_sizes, int n_in,
                              void* d_out, int out_size, void* d_ws, size_t ws_size,
                              hipStream_t stream) {
  (void)in_sizes; (void)n_in; (void)out_size; (void)ws_size;
  const void* h      = d_in[0];
  const int*  cids   = (const int*)d_in[1];
  const void* emb    = d_in[2];
  const void* Wf     = d_in[3];
  const void* bfuse  = d_in[4];
  const void* Wa1    = d_in[5];
  const void* ba1    = d_in[6];
  const void* Wb1    = d_in[7];
  const void* bb1    = d_in[8];
  const void* wc1    = d_in[9];
  const void* Wintra = d_in[11];
  const void* bintra = d_in[12];
  const void* Wa2    = d_in[13];
  const void* ba2    = d_in[14];
  const void* Wb2    = d_in[15];
  const void* bb2    = d_in[16];
  const void* wc2    = d_in[17];
  const void* Winter = d_in[19];
  const void* binter = d_in[20];
  const void* Wcls   = d_in[21];
  const void* bcls   = d_in[22];

  char* ws = (char*)d_ws;
  float*    Apart   = (float*)(ws + OFF_A);
  unsigned* gmax    = (unsigned*)(ws + OFF_SEGMAX);
  float*    denom   = (float*)(ws + OFF_DENOM);
  int*      counts  = (int*)(ws + OFF_CNT);
  float*    cfeat   = (float*)(ws + OFF_CFEAT);
  float*    cfeat2  = (float*)(ws + OFF_CFEAT2);
  int*      flag    = (int*)(ws + OFF_FLAG);
  bf16*     canon   = (bf16*)(ws + OFF_CANON);
  float*    Temb    = (float*)(ws + OFF_TEMB);
  bf16*     x       = (bf16*)(ws + OFF_X);
  bf16*     WfT     = (bf16*)(ws + OFF_WFT);
  bf16*     WgT     = (bf16*)(ws + OFF_WGT);
  bf16*     WintraT = (bf16*)(ws + OFF_WINTRAT);
  bf16*     Wa2T    = (bf16*)(ws + OFF_WA2T);
  bf16*     Wb2T    = (bf16*)(ws + OFF_WB2T);
  bf16*     WinterT = (bf16*)(ws + OFF_WINTERT);

  hipMemsetAsync(d_ws, 0, ZERO_BYTES, stream);
  k_detect<<<1, 64, 0, stream>>>((const unsigned short*)h, flag);
  k_prep<<<4646, 256, 0, stream>>>(Wf, bfuse, emb, Wa1, Wb1, Wintra, Wa2, Wb2, Winter,
                                   ba1, bb1, wc1, bintra, ba2, bb2, wc2, binter, Wcls, bcls,
                                   flag, WfT, WgT, WintraT, Wa2T, Wb2T, WinterT, Temb, canon);
  k_fuse<<<2048, 256, 0, stream>>>(h, cids, WfT, Temb, flag, x);
  k_gate1<<<2048, 256, 0, stream>>>(x, WgT, canon, Apart);
  k_segmax<<<128, 256, 0, stream>>>(Apart, cids, gmax);
  k_segsum<<<128, 256, 0, stream>>>(Apart, cids, gmax, denom, counts);
  k_cfeat<<<256, 256, 0, stream>>>(Apart, cids, gmax, denom, x, cfeat);
  k_intra<<<88, 256, 0, stream>>>(cfeat, WintraT, canon, cfeat2);
  k_tail<<<8, 256, 0, stream>>>(cfeat2, counts, Wa2T, Wb2T, WinterT, canon, flag, d_out);
}